// Round 6
// baseline (607.205 us; speedup 1.0000x reference)
//
#include <hip/hip_runtime.h>
#include <hip/hip_bf16.h>
#include <cstdint>
#include <cstddef>

typedef __fp16 f16_t;
typedef __attribute__((ext_vector_type(8))) __fp16 f16x8;
typedef __attribute__((ext_vector_type(4))) __fp16 f16x4;
typedef __attribute__((ext_vector_type(2))) __fp16 h2_t;
typedef __attribute__((ext_vector_type(4))) float floatx4;

// ---------------------------------------------------------------- helpers
__device__ __forceinline__ void async_copy_16B(const void* g, void* l) {
  __builtin_amdgcn_global_load_lds(
      (const __attribute__((address_space(1))) void*)g,
      (__attribute__((address_space(3))) void*)l, 16, 0, 0);
}

// ---------------------------------------------------------------- prep
// Fused: cast x/w_in/w_out to f16 (5242880 float4s) and build packed f16
// weight-pair table wp[p][c], p=0..127:
//   p<126 : (w[p], w[p+1]) ; p==126 : (w[126], 0) ; p==127 : (0, w[0])
__global__ __launch_bounds__(256) void prep(
    const float* __restrict__ x, const float* __restrict__ w_in,
    const float* __restrict__ w_out, const float* __restrict__ w_dw,
    f16_t* __restrict__ x_h, f16_t* __restrict__ wi_h,
    f16_t* __restrict__ wo_h, h2_t* __restrict__ wp) {
  const int tid = blockIdx.x * 256 + threadIdx.x;
  if (tid < 5242880) {
    const float* src;
    f16_t* dst;
    int off;
    if (tid < 2097152) {
      src = x; dst = x_h; off = tid;
    } else if (tid < 4194304) {
      src = w_in; dst = wi_h; off = tid - 2097152;
    } else {
      src = w_out; dst = wo_h; off = tid - 4194304;
    }
    const float4 v = *(const float4*)(src + (size_t)off * 4);
    f16x4 o;
    o.x = (f16_t)v.x; o.y = (f16_t)v.y; o.z = (f16_t)v.z; o.w = (f16_t)v.w;
    *(f16x4*)(dst + (size_t)off * 4) = o;
  } else {
    const int idx = tid - 5242880;
    if (idx < 128 * 4096) {
      const int p = idx >> 12;
      const int c = idx & 4095;
      float a, b;
      if (p < 126) {
        a = w_dw[c * 127 + p]; b = w_dw[c * 127 + p + 1];
      } else if (p == 126) {
        a = w_dw[c * 127 + 126]; b = 0.f;
      } else {
        a = 0.f; b = w_dw[c * 127 + 0];
      }
      h2_t w;
      w.x = (f16_t)a; w.y = (f16_t)b;
      wp[idx] = w;
    }
  }
}

// ---------------------------------------------------------------- GEMM (TLP)
// Occupancy-first template. 128x128 tile, BK=32, 256 thr (4 waves 2Mx2N),
// per-wave output 64x64 -> acc[4][4] = 64 AGPR. Total regs <= 128/wave
// (__launch_bounds__(256,4)) -> 4 waves/SIMD: FOUR independent blocks/CU
// (4 x 32 KB LDS = 128 KiB). The m114 mechanism: co-resident blocks at
// different loop phases cover each other's barriers/DMA drains — the TLP
// that every 1-block/CU 256^2 variant (R1-R5, all 34-40% MfmaUtil) lacked.
//
// Fragment-major LDS (verified correct in R5): each 16x32 MFMA fragment
// is one contiguous 1 KB block; ds_read_b128 at fragbase + lane*16 is
// sequential -> conflict-free (measured 0). Reader lane l expects
// (row = l&15, kgroup = l>>4); global_load_lds writes LDS linearly in
// lane order, so the global source uses the same mapping:
//   chunk q (one wave-u = one 64-chunk fragment):
//     frag = q>>6, r = q&15, g = (q>>4)&3
//     row = frag*16 + r, col = k0 + g*8 ; LDS off = q*16.
// A = 8 frags (8 KB), B = 8 frags at +8192; buffer d at d*16384.
//
// Schedule per K-tile (double buffer, 1 counted gate + 2 barriers):
//   stage(t+1 -> d^1) [4 loads/thread] ; vmcnt(4)  [tile t landed --
//   issued one full tile ago; in-order retirement] ; barrier ;
//   8 ds_read + setprio{16 MFMA} ; barrier  [reads of d done before
//   t+1 stages d]. Tail: vmcnt(0).
//
// GMODE 0 (in-proj, grid 4096 = 64m x 64n): quad-rect XCD swizzle —
//   XCD (4x2 arrangement) owns 16m x 32n tiles, filled in 8x16 quads.
// GMODE 1 (out-proj, grid 512 = 64m x 8n): XCD c owns m-tiles [8c,8c+8).
template <typename OutT, int GMODE>
__global__ __launch_bounds__(256, 4) void gemm_tlp(
    const f16_t* __restrict__ A, const f16_t* __restrict__ B,
    OutT* __restrict__ C, int M, int N, int K) {
  extern __shared__ char smem[];
  const int t = threadIdx.x;
  const int lane = t & 63;
  const int wave = t >> 6;   // 0..3
  const int wm = wave >> 1;  // 0..1 : 64-row half
  const int wn = wave & 1;   // 0..1 : 64-col half

  int m0, n0;
  if (GMODE == 0) {
    const int bid = blockIdx.x;
    const int xcd = bid & 7;
    const int l = bid >> 3;       // 0..511
    const int q2 = l >> 7;        // 0..3 : quad within XCD region
    const int im = (l >> 4) & 7;  // 0..7
    const int in_ = l & 15;       // 0..15
    const int lm = (q2 >> 1) * 8 + im;   // 0..15
    const int ln = (q2 & 1) * 16 + in_;  // 0..31
    m0 = ((xcd >> 1) * 16 + lm) * 128;
    n0 = ((xcd & 1) * 32 + ln) * 128;
  } else {
    const int bid = blockIdx.x;
    const int xcd = bid & 7;
    const int l = bid >> 3;  // 0..63
    m0 = (xcd * 8 + (l >> 3)) * 128;
    n0 = (l & 7) * 128;
  }

  auto stageTile = [&](int d, int k0) {
    char* base = smem + d * 16384;
#pragma unroll
    for (int u = 0; u < 2; ++u) {
      const int q = u * 256 + t;
      const int row = ((q >> 6) << 4) + (q & 15);  // frag*16 + r
      const int g = (q >> 4) & 3;
      async_copy_16B(A + (size_t)(m0 + row) * K + k0 + g * 8, base + q * 16);
    }
#pragma unroll
    for (int u = 0; u < 2; ++u) {
      const int q = u * 256 + t;
      const int row = ((q >> 6) << 4) + (q & 15);
      const int g = (q >> 4) & 3;
      async_copy_16B(B + (size_t)(n0 + row) * K + k0 + g * 8,
                     base + 8192 + q * 16);
    }
  };
  auto ldA = [&](int d, int frag) -> f16x8 {
    return *(const f16x8*)(smem + d * 16384 + frag * 1024 + lane * 16);
  };
  auto ldB = [&](int d, int frag) -> f16x8 {
    return *(const f16x8*)(smem + d * 16384 + 8192 + frag * 1024 +
                           lane * 16);
  };

  floatx4 acc[4][4] = {};
  const int kT = K / 32;

  stageTile(0, 0);
  for (int tt = 0; tt < kT; ++tt) {
    const int d = tt & 1;
    if (tt + 1 < kT) {
      stageTile(d ^ 1, (tt + 1) * 32);  // d^1 dead since tt-1's close bar
      asm volatile("s_waitcnt vmcnt(4)" ::: "memory");  // tile tt landed
    } else {
      asm volatile("s_waitcnt vmcnt(0)" ::: "memory");
    }
    __builtin_amdgcn_s_barrier();

    f16x8 bfr[4];
#pragma unroll
    for (int j = 0; j < 4; ++j) bfr[j] = ldB(d, wn * 4 + j);
    __builtin_amdgcn_s_setprio(1);
#pragma unroll
    for (int i = 0; i < 4; ++i) {
      const f16x8 af = ldA(d, wm * 4 + i);
#pragma unroll
      for (int j = 0; j < 4; ++j)
        acc[i][j] = __builtin_amdgcn_mfma_f32_16x16x32_f16(
            af, bfr[j], acc[i][j], 0, 0, 0);
    }
    __builtin_amdgcn_s_setprio(0);
    __builtin_amdgcn_s_barrier();  // reads of d done before tt+1 stages d
  }

  // C/D layout: col = lane&15, row = (lane>>4)*4 + reg
  const int cr = (lane >> 4) * 4;
  const int cc = lane & 15;
#pragma unroll
  for (int i = 0; i < 4; ++i)
#pragma unroll
    for (int j = 0; j < 4; ++j)
#pragma unroll
      for (int r = 0; r < 4; ++r) {
        const int row = m0 + wm * 64 + i * 16 + cr + r;
        const int col = n0 + wn * 64 + j * 16 + cc;
        C[(size_t)row * N + col] = (OutT)acc[i][j][r];
      }
}

// ---------------------------------------------------------------- conv+gate
// vg: [8192][8192] f16 (v = cols 0..4095, g = cols 4096..8191)
// wp: [128][4096] packed f16 weight pairs ; y: [8192][4096] f16
// Block: 64 channels x 128 l-outputs; 4 waves x 32 l's, lane=channel.
#define CONV_L 128
#define CPAIRS 127  // (CONV_L + 126) / 2

__global__ __launch_bounds__(256) void conv_gate(
    const f16_t* __restrict__ vg, const h2_t* __restrict__ wp,
    const float* __restrict__ b_dw, f16_t* __restrict__ y) {
  __shared__ uint32_t vtp[CPAIRS * 64];  // 32.5 KB
  __shared__ uint32_t wpl[128 * 64];     // 32 KB
  const int t = threadIdx.x;
  const int lane = t & 63;
  const int wave = t >> 6;
  const int c0 = blockIdx.x * 64;
  const int lt = blockIdx.y & 31;   // 4096/128 l-tiles
  const int b = blockIdx.y >> 5;
  const int l0 = lt * CONV_L;

  // stage weight pairs wp[p][c0..c0+63] -> wpl via global->LDS DMA
#pragma unroll
  for (int it = 0; it < 8; ++it) {
    const int q = it * 256 + t;  // 2048 16B chunks: row = q>>4, 4 words each
    async_copy_16B(wp + (size_t)(q >> 4) * 4096 + c0 + (q & 15) * 4,
                   wpl + q * 4);
  }
  // stage v rows [l0-126, l0+127] pair-interleaved (zeros for l<0)
  for (int q = t; q < CPAIRS * 8; q += 256) {
    const int m = q >> 3;
    const int oc = (q & 7) * 8;
    const int le = l0 - 126 + 2 * m;  // always even
    uint4 a = make_uint4(0u, 0u, 0u, 0u);
    uint4 bb = make_uint4(0u, 0u, 0u, 0u);
    if (le >= 0) {
      const size_t base = (size_t)(b * 4096 + le) * 8192 + c0 + oc;
      a = *(const uint4*)(vg + base);
      bb = *(const uint4*)(vg + base + 8192);
    }
    uint32_t* dst = vtp + m * 64 + oc;
    const uint32_t aw[4] = {a.x, a.y, a.z, a.w};
    const uint32_t bw[4] = {bb.x, bb.y, bb.z, bb.w};
#pragma unroll
    for (int i = 0; i < 4; ++i) {
      dst[2 * i] = (aw[i] & 0xFFFFu) | (bw[i] << 16);
      dst[2 * i + 1] = (aw[i] >> 16) | (bw[i] & 0xFFFF0000u);
    }
  }

  const int c = c0 + lane;
  const int lb = l0 + wave * 32;
  // preload gate values (independent of LDS staging; latency hidden by FIR)
  const f16_t* gp = vg + (size_t)(b * 4096 + lb) * 8192 + 4096 + c;
  f16_t gvals[32];
#pragma unroll
  for (int i = 0; i < 32; ++i) gvals[i] = gp[(size_t)i * 8192];

  __syncthreads();

  const float bias = b_dw[c];
  float acc[32];
#pragma unroll
  for (int i = 0; i < 32; ++i) acc[i] = bias;

  // single-base immediate-offset LDS pointers
  const uint32_t* vbase = vtp + wave * 16 * 64 + lane;  // pair index of v[r0]
  const uint32_t* wbase = wpl + lane;

  // ring slot m holds pair (v[r0+2m], v[r0+2m+1]); slots 0..16
  h2_t ring[17];
#pragma unroll
  for (int m = 0; m < 17; ++m)
    ring[m] = __builtin_bit_cast(h2_t, vbase[m * 64]);

  // tap 0 for odd outputs: weight (0, w[0]) = wpl row 127
  {
    const h2_t w0 = __builtin_bit_cast(h2_t, wbase[127 * 64]);
#pragma unroll
    for (int h = 0; h < 16; ++h)
      acc[2 * h + 1] =
          __builtin_amdgcn_fdot2(w0, ring[h], acc[2 * h + 1], false);
  }

  // step k: even outs use row 2k (taps 2k,2k+1); odd outs row 2k+1
#pragma unroll
  for (int k = 0; k < 64; ++k) {
    const h2_t we = __builtin_bit_cast(h2_t, wbase[(2 * k) * 64]);
#pragma unroll
    for (int h = 0; h < 16; ++h)
      acc[2 * h] =
          __builtin_amdgcn_fdot2(we, ring[(k + h) % 17], acc[2 * h], false);
    if (k < 63) {
      const h2_t wo = __builtin_bit_cast(h2_t, wbase[(2 * k + 1) * 64]);
#pragma unroll
      for (int h = 0; h < 16; ++h)
        acc[2 * h + 1] = __builtin_amdgcn_fdot2(wo, ring[(k + 1 + h) % 17],
                                                acc[2 * h + 1], false);
      if (k < 62)  // slide: slot k%17 <- pair k+17
        ring[k % 17] = __builtin_bit_cast(h2_t, vbase[(17 + k) * 64]);
    }
  }

  f16_t* yp = y + (size_t)(b * 4096 + lb) * 4096 + c;
#pragma unroll
  for (int i = 0; i < 32; ++i) {
    const float gv = (float)gvals[i];
    const float v = acc[i];
    const float sv = v / (1.f + __expf(-v));
    const float sg = gv / (1.f + __expf(-gv));
    yp[(size_t)i * 4096] = (f16_t)(sv * sg);
  }
}

// ---------------------------------------------------------------- launch
extern "C" void kernel_launch(void* const* d_in, const int* in_sizes, int n_in,
                              void* d_out, int out_size, void* d_ws,
                              size_t ws_size, hipStream_t stream) {
  const float* x     = (const float*)d_in[0];  // [2,4096,1024]
  const float* w_in  = (const float*)d_in[1];  // [8192,1024]
  const float* w_dw  = (const float*)d_in[2];  // [4096,127]
  const float* b_dw  = (const float*)d_in[3];  // [4096]
  const float* w_out = (const float*)d_in[4];  // [1024,4096]
  float* out = (float*)d_out;                  // [2,4096,1024]

  char* p = (char*)d_ws;
  f16_t* x_h  = (f16_t*)p; p += (size_t)8192 * 1024 * 2;
  f16_t* wi_h = (f16_t*)p; p += (size_t)8192 * 1024 * 2;
  f16_t* wo_h = (f16_t*)p; p += (size_t)1024 * 4096 * 2;
  h2_t*  wp   = (h2_t*)p;  p += (size_t)128 * 4096 * 4;
  f16_t* vg   = (f16_t*)p; p += (size_t)8192 * 8192 * 2;
  f16_t* y    = (f16_t*)p; p += (size_t)8192 * 4096 * 2;

  // fused casts + packed weight-pair build
  prep<<<22528, 256, 0, stream>>>(x, w_in, w_out, w_dw, x_h, wi_h, wo_h, wp);

  // vg[8192,8192] = x[8192,1024] @ w_in[8192,1024]^T
  // 128^2 tile, 4 blocks/CU TLP, grid 4096 (64x64), quad-rect XCD swizzle
  hipFuncSetAttribute((const void*)gemm_tlp<f16_t, 0>,
                      hipFuncAttributeMaxDynamicSharedMemorySize, 32768);
  gemm_tlp<f16_t, 0><<<4096, 256, 32768, stream>>>(x_h, wi_h, vg,
                                                   8192, 8192, 1024);

  // y = silu(causal_dwconv(v)+b) * silu(g)
  conv_gate<<<dim3(64, 64), 256, 0, stream>>>(vg, wp, b_dw, y);

  // out[8192,1024] = y[8192,4096] @ w_out[1024,4096]^T (same TLP template)
  hipFuncSetAttribute((const void*)gemm_tlp<float, 1>,
                      hipFuncAttributeMaxDynamicSharedMemorySize, 32768);
  gemm_tlp<float, 1><<<512, 256, 32768, stream>>>(y, wo_h, out,
                                                  8192, 1024, 4096);
}

// Round 7
// 451.997 us; speedup vs baseline: 1.3434x; 1.3434x over previous
//
#include <hip/hip_runtime.h>
#include <hip/hip_bf16.h>
#include <cstdint>
#include <cstddef>

typedef __fp16 f16_t;
typedef __attribute__((ext_vector_type(8))) __fp16 f16x8;
typedef __attribute__((ext_vector_type(4))) __fp16 f16x4;
typedef __attribute__((ext_vector_type(2))) __fp16 h2_t;
typedef __attribute__((ext_vector_type(4))) float floatx4;

// ---------------------------------------------------------------- helpers
__device__ __forceinline__ void async_copy_16B(const void* g, void* l) {
  __builtin_amdgcn_global_load_lds(
      (const __attribute__((address_space(1))) void*)g,
      (__attribute__((address_space(3))) void*)l, 16, 0, 0);
}

// ---------------------------------------------------------------- prep
// Fused: cast x/w_in/w_out to f16 (5242880 float4s) and build packed f16
// weight-pair table wp[p][c], p=0..127:
//   p<126 : (w[p], w[p+1]) ; p==126 : (w[126], 0) ; p==127 : (0, w[0])
__global__ __launch_bounds__(256) void prep(
    const float* __restrict__ x, const float* __restrict__ w_in,
    const float* __restrict__ w_out, const float* __restrict__ w_dw,
    f16_t* __restrict__ x_h, f16_t* __restrict__ wi_h,
    f16_t* __restrict__ wo_h, h2_t* __restrict__ wp) {
  const int tid = blockIdx.x * 256 + threadIdx.x;
  if (tid < 5242880) {
    const float* src;
    f16_t* dst;
    int off;
    if (tid < 2097152) {
      src = x; dst = x_h; off = tid;
    } else if (tid < 4194304) {
      src = w_in; dst = wi_h; off = tid - 2097152;
    } else {
      src = w_out; dst = wo_h; off = tid - 4194304;
    }
    const float4 v = *(const float4*)(src + (size_t)off * 4);
    f16x4 o;
    o.x = (f16_t)v.x; o.y = (f16_t)v.y; o.z = (f16_t)v.z; o.w = (f16_t)v.w;
    *(f16x4*)(dst + (size_t)off * 4) = o;
  } else {
    const int idx = tid - 5242880;
    if (idx < 128 * 4096) {
      const int p = idx >> 12;
      const int c = idx & 4095;
      float a, b;
      if (p < 126) {
        a = w_dw[c * 127 + p]; b = w_dw[c * 127 + p + 1];
      } else if (p == 126) {
        a = w_dw[c * 127 + 126]; b = 0.f;
      } else {
        a = 0.f; b = w_dw[c * 127 + 0];
      }
      h2_t w;
      w.x = (f16_t)a; w.y = (f16_t)b;
      wp[idx] = w;
    }
  }
}

// ---------------------------------------------------------------- GEMM1
// (R3 best: 152 us, MfmaUtil 40, conflicts 0 — reverted verbatim)
// 256x256 tile, BK=64, 8 waves (2M x 4N), ONE phase per K-tile:
//   stage(t+1 -> d^1) -> s_waitcnt vmcnt(8) -> barrier
//   -> ds_read frags + 64 MFMA/wave -> barrier
// 128 KiB LDS double buffer, XOR-swizzled rows (linear DMA dest +
// inverse-swizzled global source). Quad-rect XCD swizzle.
__global__ __launch_bounds__(512, 2) void gemm256_1p(
    const f16_t* __restrict__ A, const f16_t* __restrict__ B,
    f16_t* __restrict__ C, int M, int N, int K) {
  extern __shared__ char smem[];
  const int t = threadIdx.x;
  const int lane = t & 63;
  const int wave = t >> 6;
  const int wm = wave >> 2;  // 0..1 : 128-row half
  const int wn = wave & 3;   // 0..3 : 64-col strip

  const int bid = blockIdx.x;
  const int xcd = bid & 7;
  const int l = bid >> 3;      // 0..127
  const int quad = l >> 5;     // 0..3
  const int qm = (l >> 3) & 3; // 0..3
  const int qn = l & 7;        // 0..7
  const int m0 = ((xcd >> 1) * 8 + (quad >> 1) * 4 + qm) * 256;
  const int n0 = ((xcd & 1) * 16 + (quad & 1) * 8 + qn) * 256;

  const int fr = lane & 15;
  const int ks = lane >> 4;  // k8-group within K=32 half

  auto stageTile = [&](int d, int k0) {
#pragma unroll
    for (int u = 0; u < 4; ++u) {
      const int q = u * 512 + t;
      const int row = q >> 3, slot = q & 7;
      const int col = (slot ^ (row & 7)) * 8;  // inverse-swizzled source
      async_copy_16B(A + (size_t)(m0 + row) * K + k0 + col,
                     smem + d * 65536 + row * 128 + slot * 16);
    }
#pragma unroll
    for (int u = 0; u < 4; ++u) {
      const int q = u * 512 + t;
      const int row = q >> 3, slot = q & 7;
      const int col = (slot ^ (row & 7)) * 8;
      async_copy_16B(B + (size_t)(n0 + row) * K + k0 + col,
                     smem + d * 65536 + 32768 + row * 128 + slot * 16);
    }
  };
  auto ldA = [&](int d, int R, int kslot) -> f16x8 {
    return *(const f16x8*)(smem + d * 65536 + R * 128 +
                           ((kslot ^ (R & 7)) << 4));
  };
  auto ldB = [&](int d, int R, int kslot) -> f16x8 {
    return *(const f16x8*)(smem + d * 65536 + 32768 + R * 128 +
                           ((kslot ^ (R & 7)) << 4));
  };

  floatx4 acc[8][4] = {};
  const int kTiles = K / 64;  // 16

  stageTile(0, 0);
  for (int tt = 0; tt < kTiles; ++tt) {
    const int d = tt & 1;
    const bool pf = (tt + 1 < kTiles);
    if (pf) {
      stageTile(d ^ 1, (tt + 1) * 64);  // d^1 dead since tt-1's close bar
      asm volatile("s_waitcnt vmcnt(8)" ::: "memory");  // tile tt landed
    } else {
      asm volatile("s_waitcnt vmcnt(0)" ::: "memory");
    }
    __builtin_amdgcn_s_barrier();

    f16x8 bf[4][2];
#pragma unroll
    for (int j = 0; j < 4; ++j)
#pragma unroll
      for (int kh = 0; kh < 2; ++kh)
        bf[j][kh] = ldB(d, wn * 64 + j * 16 + fr, kh * 4 + ks);
    __builtin_amdgcn_s_setprio(1);
#pragma unroll
    for (int ii = 0; ii < 8; ++ii) {
      const f16x8 af0 = ldA(d, wm * 128 + ii * 16 + fr, ks);
      const f16x8 af1 = ldA(d, wm * 128 + ii * 16 + fr, 4 + ks);
#pragma unroll
      for (int j = 0; j < 4; ++j)
        acc[ii][j] = __builtin_amdgcn_mfma_f32_16x16x32_f16(
            af0, bf[j][0], acc[ii][j], 0, 0, 0);
#pragma unroll
      for (int j = 0; j < 4; ++j)
        acc[ii][j] = __builtin_amdgcn_mfma_f32_16x16x32_f16(
            af1, bf[j][1], acc[ii][j], 0, 0, 0);
    }
    __builtin_amdgcn_s_setprio(0);
    __builtin_amdgcn_s_barrier();  // all reads of d done before t+1 stages d
  }

  // C/D layout: col = lane&15, row = (lane>>4)*4 + reg
  const int cr = (lane >> 4) * 4;
  const int cc = lane & 15;
#pragma unroll
  for (int i = 0; i < 8; ++i)
#pragma unroll
    for (int j = 0; j < 4; ++j)
#pragma unroll
      for (int r = 0; r < 4; ++r) {
        const int row = m0 + wm * 128 + i * 16 + cr + r;
        const int col = n0 + wn * 64 + j * 16 + cc;
        C[(size_t)row * N + col] = (f16_t)acc[i][j][r];
      }
}

// ---------------------------------------------------------------- GEMM2
// (R3 best — reverted verbatim.) BM=256, BN=128, BK=64, 512 thr, 96 KiB
// LDS double buffer, 1-phase/tile, counted vmcnt(6). Grid = 256 blocks
// (32m x 8n), XCD-mapped. Per-wave output 128x32 (acc[8][2]).
__global__ __launch_bounds__(512, 2) void gemmN128_1p(
    const f16_t* __restrict__ A, const f16_t* __restrict__ B,
    float* __restrict__ C, int M, int N, int K) {
  extern __shared__ char smem[];
  const int t = threadIdx.x;
  const int lane = t & 63;
  const int wave = t >> 6;
  const int wm = wave >> 2;  // 0..1
  const int wn = wave & 3;   // 0..3

  const int bid = blockIdx.x;
  const int xcd = bid & 7;
  const int l = bid >> 3;               // 0..31
  const int m0 = (xcd * 4 + (l >> 3)) * 256;  // 32 m-tiles
  const int n0 = (l & 7) * 128;               // 8 n-tiles

  const int fr = lane & 15;
  const int ks = lane >> 4;

  auto stageTile = [&](int d, int k0) {
#pragma unroll
    for (int u = 0; u < 4; ++u) {  // A: 256x64 = 2048 chunks
      const int q = u * 512 + t;
      const int row = q >> 3, slot = q & 7;
      const int col = (slot ^ (row & 7)) * 8;
      async_copy_16B(A + (size_t)(m0 + row) * K + k0 + col,
                     smem + d * 49152 + row * 128 + slot * 16);
    }
#pragma unroll
    for (int u = 0; u < 2; ++u) {  // B: 128x64 = 1024 chunks
      const int q = u * 512 + t;
      const int row = q >> 3, slot = q & 7;
      const int col = (slot ^ (row & 7)) * 8;
      async_copy_16B(B + (size_t)(n0 + row) * K + k0 + col,
                     smem + d * 49152 + 32768 + row * 128 + slot * 16);
    }
  };
  auto ldA = [&](int d, int R, int kslot) -> f16x8 {
    return *(const f16x8*)(smem + d * 49152 + R * 128 +
                           ((kslot ^ (R & 7)) << 4));
  };
  auto ldB = [&](int d, int R, int kslot) -> f16x8 {
    return *(const f16x8*)(smem + d * 49152 + 32768 + R * 128 +
                           ((kslot ^ (R & 7)) << 4));
  };

  floatx4 acc[8][2] = {};
  const int kTiles = K / 64;  // 64

  stageTile(0, 0);
  for (int tt = 0; tt < kTiles; ++tt) {
    const int d = tt & 1;
    const bool pf = (tt + 1 < kTiles);
    if (pf) {
      stageTile(d ^ 1, (tt + 1) * 64);
      asm volatile("s_waitcnt vmcnt(6)" ::: "memory");  // tile tt landed
    } else {
      asm volatile("s_waitcnt vmcnt(0)" ::: "memory");
    }
    __builtin_amdgcn_s_barrier();

    f16x8 bf[2][2];
#pragma unroll
    for (int j = 0; j < 2; ++j)
#pragma unroll
      for (int kh = 0; kh < 2; ++kh)
        bf[j][kh] = ldB(d, wn * 32 + j * 16 + fr, kh * 4 + ks);
    __builtin_amdgcn_s_setprio(1);
#pragma unroll
    for (int ii = 0; ii < 8; ++ii) {
      const f16x8 af0 = ldA(d, wm * 128 + ii * 16 + fr, ks);
      const f16x8 af1 = ldA(d, wm * 128 + ii * 16 + fr, 4 + ks);
#pragma unroll
      for (int j = 0; j < 2; ++j)
        acc[ii][j] = __builtin_amdgcn_mfma_f32_16x16x32_f16(
            af0, bf[j][0], acc[ii][j], 0, 0, 0);
#pragma unroll
      for (int j = 0; j < 2; ++j)
        acc[ii][j] = __builtin_amdgcn_mfma_f32_16x16x32_f16(
            af1, bf[j][1], acc[ii][j], 0, 0, 0);
    }
    __builtin_amdgcn_s_setprio(0);
    __builtin_amdgcn_s_barrier();
  }

  const int cr = (lane >> 4) * 4;
  const int cc = lane & 15;
#pragma unroll
  for (int i = 0; i < 8; ++i)
#pragma unroll
    for (int j = 0; j < 2; ++j)
#pragma unroll
      for (int r = 0; r < 4; ++r) {
        const int row = m0 + wm * 128 + i * 16 + cr + r;
        const int col = n0 + wn * 32 + j * 16 + cc;
        C[(size_t)row * N + col] = acc[i][j][r];
      }
}

// ---------------------------------------------------------------- conv+gate
// ROLLING-STRIP version. vg: [8192][8192] f16 (v cols 0..4095, g cols
// 4096..8191); wp: [128][4096] packed pairs; y: [8192][4096] f16.
// Grid 64x8 = 512 blocks (2/CU): block = (64-ch group c0, b, 1024-l strip).
// Loops over 8 chunks of 128 l. wp (32 KB) staged ONCE per block (was:
// once per 128-l tile -> wp traffic 128 MB -> 16 MB). vtp staging writes
// packed as 2x uint4 (b128) instead of 8x b32 (8-way bank conflict fix).
// FIR inner body identical to the verified version.
#define CONV_L 128
#define CPAIRS 127  // (CONV_L + 126) / 2

__global__ __launch_bounds__(256) void conv_gate(
    const f16_t* __restrict__ vg, const h2_t* __restrict__ wp,
    const float* __restrict__ b_dw, f16_t* __restrict__ y) {
  __shared__ uint32_t vtp[CPAIRS * 64];  // 32.5 KB
  __shared__ uint32_t wpl[128 * 64];     // 32 KB
  const int t = threadIdx.x;
  const int lane = t & 63;
  const int wave = t >> 6;
  const int c0 = blockIdx.x * 64;
  const int b = blockIdx.y >> 2;   // batch
  const int lh = blockIdx.y & 3;   // 1024-l strip

  // stage weight pairs wp[p][c0..c0+63] -> wpl ONCE (global->LDS DMA)
#pragma unroll
  for (int it = 0; it < 8; ++it) {
    const int q = it * 256 + t;  // 2048 16B chunks: row = q>>4, 4 words each
    async_copy_16B(wp + (size_t)(q >> 4) * 4096 + c0 + (q & 15) * 4,
                   wpl + q * 4);
  }

  const int c = c0 + lane;
  const float bias = b_dw[c];
  // single-base immediate-offset LDS pointers (loop-invariant)
  const uint32_t* vbase = vtp + wave * 16 * 64 + lane;  // pair idx of v[r0]
  const uint32_t* wbase = wpl + lane;

  for (int j = 0; j < 8; ++j) {
    const int l0 = lh * 1024 + j * CONV_L;

    // stage v rows [l0-126, l0+127] pair-interleaved (zeros for l<0)
    for (int q = t; q < CPAIRS * 8; q += 256) {
      const int m = q >> 3;
      const int oc = (q & 7) * 8;
      const int le = l0 - 126 + 2 * m;  // always even
      uint4 a = make_uint4(0u, 0u, 0u, 0u);
      uint4 bb = make_uint4(0u, 0u, 0u, 0u);
      if (le >= 0) {
        const size_t base = (size_t)(b * 4096 + le) * 8192 + c0 + oc;
        a = *(const uint4*)(vg + base);
        bb = *(const uint4*)(vg + base + 8192);
      }
      const uint32_t aw[4] = {a.x, a.y, a.z, a.w};
      const uint32_t bw[4] = {bb.x, bb.y, bb.z, bb.w};
      uint32_t dw[8];
#pragma unroll
      for (int i = 0; i < 4; ++i) {
        dw[2 * i] = (aw[i] & 0xFFFFu) | (bw[i] << 16);
        dw[2 * i + 1] = (aw[i] >> 16) | (bw[i] & 0xFFFF0000u);
      }
      uint32_t* dst = vtp + q * 8;  // == m*64 + oc (contiguous 8 words)
      *(uint4*)dst = make_uint4(dw[0], dw[1], dw[2], dw[3]);
      *(uint4*)(dst + 4) = make_uint4(dw[4], dw[5], dw[6], dw[7]);
    }

    const int lb = l0 + wave * 32;
    // preload gate values (latency hidden under staging + FIR)
    const f16_t* gp = vg + (size_t)(b * 4096 + lb) * 8192 + 4096 + c;
    f16_t gvals[32];
#pragma unroll
    for (int i = 0; i < 32; ++i) gvals[i] = gp[(size_t)i * 8192];

    __syncthreads();  // staging (and, at j=0, wpl DMA) visible to all

    float acc[32];
#pragma unroll
    for (int i = 0; i < 32; ++i) acc[i] = bias;

    // ring slot m holds pair (v[r0+2m], v[r0+2m+1]); slots 0..16
    h2_t ring[17];
#pragma unroll
    for (int m = 0; m < 17; ++m)
      ring[m] = __builtin_bit_cast(h2_t, vbase[m * 64]);

    // tap 0 for odd outputs: weight (0, w[0]) = wpl row 127
    {
      const h2_t w0 = __builtin_bit_cast(h2_t, wbase[127 * 64]);
#pragma unroll
      for (int h = 0; h < 16; ++h)
        acc[2 * h + 1] =
            __builtin_amdgcn_fdot2(w0, ring[h], acc[2 * h + 1], false);
    }

    // step k: even outs use row 2k (taps 2k,2k+1); odd outs row 2k+1
#pragma unroll
    for (int k = 0; k < 64; ++k) {
      const h2_t we = __builtin_bit_cast(h2_t, wbase[(2 * k) * 64]);
#pragma unroll
      for (int h = 0; h < 16; ++h)
        acc[2 * h] =
            __builtin_amdgcn_fdot2(we, ring[(k + h) % 17], acc[2 * h], false);
      if (k < 63) {
        const h2_t wo = __builtin_bit_cast(h2_t, wbase[(2 * k + 1) * 64]);
#pragma unroll
        for (int h = 0; h < 16; ++h)
          acc[2 * h + 1] = __builtin_amdgcn_fdot2(wo, ring[(k + 1 + h) % 17],
                                                  acc[2 * h + 1], false);
        if (k < 62)  // slide: slot k%17 <- pair k+17
          ring[k % 17] = __builtin_bit_cast(h2_t, vbase[(17 + k) * 64]);
      }
    }

    f16_t* yp = y + (size_t)(b * 4096 + lb) * 4096 + c;
#pragma unroll
    for (int i = 0; i < 32; ++i) {
      const float gv = (float)gvals[i];
      const float v = acc[i];
      const float sv = v / (1.f + __expf(-v));
      const float sg = gv / (1.f + __expf(-gv));
      yp[(size_t)i * 4096] = (f16_t)(sv * sg);
    }

    __syncthreads();  // all waves done reading vtp before next restage
  }
}

// ---------------------------------------------------------------- launch
extern "C" void kernel_launch(void* const* d_in, const int* in_sizes, int n_in,
                              void* d_out, int out_size, void* d_ws,
                              size_t ws_size, hipStream_t stream) {
  const float* x     = (const float*)d_in[0];  // [2,4096,1024]
  const float* w_in  = (const float*)d_in[1];  // [8192,1024]
  const float* w_dw  = (const float*)d_in[2];  // [4096,127]
  const float* b_dw  = (const float*)d_in[3];  // [4096]
  const float* w_out = (const float*)d_in[4];  // [1024,4096]
  float* out = (float*)d_out;                  // [2,4096,1024]

  char* p = (char*)d_ws;
  f16_t* x_h  = (f16_t*)p; p += (size_t)8192 * 1024 * 2;
  f16_t* wi_h = (f16_t*)p; p += (size_t)8192 * 1024 * 2;
  f16_t* wo_h = (f16_t*)p; p += (size_t)1024 * 4096 * 2;
  h2_t*  wp   = (h2_t*)p;  p += (size_t)128 * 4096 * 4;
  f16_t* vg   = (f16_t*)p; p += (size_t)8192 * 8192 * 2;
  f16_t* y    = (f16_t*)p; p += (size_t)8192 * 4096 * 2;

  // fused casts + packed weight-pair build
  prep<<<22528, 256, 0, stream>>>(x, w_in, w_out, w_dw, x_h, wi_h, wo_h, wp);

  // vg[8192,8192] = x[8192,1024] @ w_in[8192,1024]^T  (R3 best config)
  hipFuncSetAttribute(reinterpret_cast<const void*>(gemm256_1p),
                      hipFuncAttributeMaxDynamicSharedMemorySize, 131072);
  gemm256_1p<<<1024, 512, 131072, stream>>>(x_h, wi_h, vg, 8192, 8192, 1024);

  // y = silu(causal_dwconv(v)+b) * silu(g)  (rolling-strip, 512 blocks)
  conv_gate<<<dim3(64, 8), 256, 0, stream>>>(vg, wp, b_dw, y);

  // out[8192,1024] = y[8192,4096] @ w_out[1024,4096]^T (R3 best config)
  hipFuncSetAttribute(reinterpret_cast<const void*>(gemmN128_1p),
                      hipFuncAttributeMaxDynamicSharedMemorySize, 98304);
  gemmN128_1p<<<256, 512, 98304, stream>>>(y, wo_h, out, 8192, 1024, 4096);
}